// Round 11
// baseline (177.050 us; speedup 1.0000x reference)
//
#include <hip/hip_runtime.h>

typedef __attribute__((ext_vector_type(8))) short bf16x8;
typedef __attribute__((ext_vector_type(4))) float f32x4;

#if __has_builtin(__builtin_amdgcn_exp2f)
#define EXP2F(x) __builtin_amdgcn_exp2f(x)
#else
extern "C" __device__ float __ocml_native_exp2_f32(float);
#define EXP2F(x) __ocml_native_exp2_f32(x)
#endif

// qscale = log2(e) / 32, baked into Q columns of W_qkv
#define QSCALE 0.04508422002778011f
#define NS 2048

__device__ __forceinline__ ushort f32_to_bf16(float f) {
  union { float f; unsigned u; } x; x.f = f;
  unsigned r = x.u + 0x7fffu + ((x.u >> 16) & 1u);
  return (ushort)(r >> 16);
}

// pack two f32 -> one dword of two bf16 (lo = f0, hi = f1)
__device__ __forceinline__ unsigned pack_bf16(float f0, float f1) {
  union { float f; unsigned u; } a, b;
  a.f = f0; b.f = f1;
  return __builtin_amdgcn_perm(b.u + 0x8000u, a.u + 0x8000u, 0x07060302u);
}

// async global->LDS, 16B per lane; lds base must be wave-uniform
__device__ __forceinline__ void load16_to_lds(const void* g, void* l) {
  __builtin_amdgcn_global_load_lds(
      (const __attribute__((address_space(1))) unsigned int*)(
          reinterpret_cast<uintptr_t>(g)),
      (__attribute__((address_space(3))) unsigned int*)(
          reinterpret_cast<uintptr_t>(l)),
      16, 0, 0);
}

// ---------------------------------------------------------------------------
// prep: blocks [0,2048): convert x -> bf16 (8 elems/thread)
//       blocks [2048,5120): W_qkv^T -> wqkvT [3072][1024], Q cols scaled
//       blocks [5120,6144): W_out^T -> woutT [1024][1024]
// ---------------------------------------------------------------------------
__global__ __launch_bounds__(256) void prep(
    const float* __restrict__ x, const float* __restrict__ Wqkv,
    const float* __restrict__ Wout,
    ushort* __restrict__ xb, ushort* __restrict__ wqkvT,
    ushort* __restrict__ woutT)
{
  __shared__ ushort tile[32][33];
  const int bid = blockIdx.x, t = threadIdx.x;
  if (bid < 2048) {
    size_t i = (size_t)bid * 256 + t;
    const float4* p = (const float4*)(x + i * 8);
    float4 a = p[0], b = p[1];
    union { uint4 v; ushort s[8]; } u;
    u.s[0] = f32_to_bf16(a.x); u.s[1] = f32_to_bf16(a.y);
    u.s[2] = f32_to_bf16(a.z); u.s[3] = f32_to_bf16(a.w);
    u.s[4] = f32_to_bf16(b.x); u.s[5] = f32_to_bf16(b.y);
    u.s[6] = f32_to_bf16(b.z); u.s[7] = f32_to_bf16(b.w);
    *(uint4*)(xb + i * 8) = u.v;
  } else if (bid < 5120) {
    int tb = bid - 2048;                 // 96 col-tiles x 32 row-tiles
    int cb = (tb % 96) * 32, rb = (tb / 96) * 32;
    int tx = t & 31, ty = t >> 5;
    float s = (cb + tx) < 1024 ? QSCALE : 1.0f;
#pragma unroll
    for (int k = 0; k < 4; ++k)
      tile[ty + 8 * k][tx] =
          f32_to_bf16(Wqkv[(size_t)(rb + ty + 8 * k) * 3072 + cb + tx] * s);
    __syncthreads();
#pragma unroll
    for (int k = 0; k < 4; ++k)
      wqkvT[(size_t)(cb + ty + 8 * k) * 1024 + rb + tx] = tile[tx][ty + 8 * k];
  } else {
    int tb = bid - 5120;                 // 32 x 32 tiles
    int cb = (tb & 31) * 32, rb = (tb >> 5) * 32;
    int tx = t & 31, ty = t >> 5;
#pragma unroll
    for (int k = 0; k < 4; ++k)
      tile[ty + 8 * k][tx] =
          f32_to_bf16(Wout[(size_t)(rb + ty + 8 * k) * 1024 + cb + tx]);
    __syncthreads();
#pragma unroll
    for (int k = 0; k < 4; ++k)
      woutT[(size_t)(cb + ty + 8 * k) * 1024 + rb + tx] = tile[tx][ty + 8 * k];
  }
}

// ---------------------------------------------------------------------------
// GEMM core: C tile = A[M,K] * Bt[N,K]^T (+ fp32 bias). bf16 in, fp32 accum.
// TM x 128 tile, BK in {32,64}, double-buffered global_load_lds staging,
// single barrier per K-iter. LDS rows XOR-chunk-swizzled (conflict-free b128).
// ---------------------------------------------------------------------------
template <int TM, int BK>
__device__ __forceinline__ void stage_ab(
    const ushort* __restrict__ A, const ushort* __restrict__ Bt,
    int K, int mbase, int nbase, int kb,
    ushort* __restrict__ sA, ushort* __restrict__ sB,
    int w, int lrow, int gofs)
{
  constexpr int ROWS = (BK == 32) ? 16 : 8;  // rows per wave-op (1KB)
#pragma unroll
  for (int r = 0; r < TM / (ROWS * 4); ++r) {
    int rb = w * (TM / 4) + r * ROWS;
    load16_to_lds(&A[(size_t)(mbase + rb + lrow) * K + kb + gofs], &sA[rb * BK]);
  }
#pragma unroll
  for (int r = 0; r < 128 / (ROWS * 4); ++r) {
    int rb = w * 32 + r * ROWS;
    load16_to_lds(&Bt[(size_t)(nbase + rb + lrow) * K + kb + gofs], &sB[rb * BK]);
  }
}

template <int TM, int BK, typename TC>
__device__ __forceinline__ void gemm_core(
    const ushort* __restrict__ A, const ushort* __restrict__ Bt,
    const float* __restrict__ bias, TC* __restrict__ C,
    int N, int K, int mbase, int nbase,
    ushort* __restrict__ sA0, ushort* __restrict__ sB0,
    ushort* __restrict__ sA1, ushort* __restrict__ sB1)
{
  constexpr int MT = TM / 32;
  const int t = threadIdx.x;
  const int lane = t & 63, w = t >> 6;
  const int quad = lane >> 4, l16 = lane & 15;
  const int wr = w >> 1, wc = w & 1;
  const int lrow = (BK == 32) ? (lane >> 2) : (lane >> 3);
  const int gofs = (BK == 32)
      ? (((lane & 3) ^ ((lane >> 3) & 3)) * 8)
      : (((lane & 7) ^ (lane >> 3)) * 8);
  const int rswz = (BK == 32) ? ((l16 >> 1) & 3) : (l16 & 7);

  f32x4 acc[MT][4];
#pragma unroll
  for (int i = 0; i < MT; ++i)
#pragma unroll
    for (int j = 0; j < 4; ++j)
      acc[i][j] = (f32x4){0.f, 0.f, 0.f, 0.f};

  stage_ab<TM, BK>(A, Bt, K, mbase, nbase, 0, sA0, sB0, w, lrow, gofs);

  for (int kb = 0; kb < K; kb += BK) {
    const bool odd = (kb / BK) & 1;
    ushort* sA = odd ? sA1 : sA0;
    ushort* sB = odd ? sB1 : sB0;
    ushort* pA = odd ? sA0 : sA1;
    ushort* pB = odd ? sB0 : sB1;
    __syncthreads();
    if (kb + BK < K)
      stage_ab<TM, BK>(A, Bt, K, mbase, nbase, kb + BK, pA, pB, w, lrow, gofs);

#pragma unroll
    for (int c = 0; c < BK / 32; ++c) {
      bf16x8 af[MT], bfr[4];
#pragma unroll
      for (int mt = 0; mt < MT; ++mt)
        af[mt] = *(const bf16x8*)&sA[(wr * (TM / 2) + mt * 16 + l16) * BK +
                                     (((c * 4 + quad) ^ rswz) * 8)];
#pragma unroll
      for (int nt = 0; nt < 4; ++nt)
        bfr[nt] = *(const bf16x8*)&sB[(wc * 64 + nt * 16 + l16) * BK +
                                      (((c * 4 + quad) ^ rswz) * 8)];
#pragma unroll
      for (int mt = 0; mt < MT; ++mt)
#pragma unroll
        for (int nt = 0; nt < 4; ++nt)
          acc[mt][nt] = __builtin_amdgcn_mfma_f32_16x16x32_bf16(
              af[mt], bfr[nt], acc[mt][nt], 0, 0, 0);
    }
  }

#pragma unroll
  for (int mt = 0; mt < MT; ++mt) {
#pragma unroll
    for (int nt = 0; nt < 4; ++nt) {
      int col = nbase + wc * 64 + nt * 16 + l16;
      float bv = bias ? bias[col] : 0.f;
#pragma unroll
      for (int ri = 0; ri < 4; ++ri) {
        int row = mbase + wr * (TM / 2) + mt * 16 + quad * 4 + ri;
        float val = acc[mt][nt][ri] + bv;
        if constexpr (__is_same(TC, float))
          C[(size_t)row * N + col] = val;
        else
          C[(size_t)row * N + col] = f32_to_bf16(val);
      }
    }
  }
}

// blocks [0,512):    qk = xb @ WqkvT[0:2048]^T  -> [4096][2048], TM=128
// blocks [512,1024): V^T = WqkvT[2048:] @ xb^T  -> [1024][4096], TM=64
// One kernel so both block types co-schedule (4 blocks/CU mixed); raw LDS
// carve: TM=128 path uses 32KB (4x8KB), TM=64 path uses 24KB of the same.
// XCD swizzle on both sub-grids.
__global__ __launch_bounds__(256, 4) void gemm_qkvt(
    const ushort* __restrict__ xb, const ushort* __restrict__ wqkvT,
    ushort* __restrict__ qk, ushort* __restrict__ vtbuf)
{
  __shared__ ushort smem[128 * 32 * 4];  // 32 KB
  const int bid = blockIdx.x;
  if (bid < 512) {
    int j = bid >> 3;                       // 0..63
    int m = (bid & 7) * 4 + (j & 3);        // 0..31
    int n = j >> 2;                         // 0..15
    gemm_core<128, 32, ushort>(xb, wqkvT, nullptr, qk, 2048, 1024,
                               m * 128, n * 128,
                               smem, smem + 4096, smem + 8192, smem + 12288);
  } else {
    const int id = bid - 512;               // 0..511
    int j = id >> 3;                        // 0..63
    int m = (id & 7) * 2 + (j & 1);         // 0..15  (1024/64)
    int n = j >> 1;                         // 0..31  (4096/128)
    // carve: A0 2K elems, B0 4K, A1 2K, B1 4K  (12K elems = 24KB)
    gemm_core<64, 32, ushort>(wqkvT + (size_t)2048 * 1024, xb, nullptr, vtbuf,
                              4096, 1024, m * 64, n * 128,
                              smem, smem + 2048, smem + 6144, smem + 8192);
  }
}

// out = attnb @ WoutT^T + b_out (fp32). 64x128 tiles -> 512 blocks (64m x 8n).
__global__ __launch_bounds__(256) void gemm_out(
    const ushort* __restrict__ attnb, const ushort* __restrict__ woutT,
    const float* __restrict__ bias, float* __restrict__ out)
{
  __shared__ ushort sA0[64 * 64], sB0[128 * 64];
  __shared__ ushort sA1[64 * 64], sB1[128 * 64];
  const int bid = blockIdx.x;
  int m = (bid & 7) * 8 + ((bid >> 3) & 7);  // 0..63
  int n = bid >> 6;                          // 0..7
  gemm_core<64, 64, float>(attnb, woutT, bias, out, 1024, 1024,
                           m * 64, n * 128, sA0, sB0, sA1, sB1);
}

// ---------------------------------------------------------------------------
// Flash attention (unchanged from R10): S^T formulation, no-max softmax,
// 512 threads = 8 waves x 16 q-rows, pattern mask incl. (w&1)*16 term,
// K/V double-buffered global_load_lds, P via per-wave LDS, l via ones-MFMA.
// ---------------------------------------------------------------------------
__device__ __forceinline__ void stage_kv(
    const ushort* __restrict__ qk, const ushort* __restrict__ vt,
    ushort* sKb, ushort* sVb, int b, int h, int kvbase,
    int w, int rowK, int csw)
{
  int rk = w * 8 + rowK;  // 8 waves x 8 rows = 64
  load16_to_lds(&qk[((size_t)(b * NS + kvbase + rk)) * 2048 + 1024 + h * 64 + csw],
                &sKb[(w * 8) * 64]);
  load16_to_lds(&vt[((size_t)(h * 64 + rk)) * 4096 + b * 2048 + kvbase + csw],
                &sVb[(w * 8) * 64]);
}

__global__ __launch_bounds__(512, 4) void attn_kernel(
    const ushort* __restrict__ qk, const ushort* __restrict__ vt,
    ushort* __restrict__ attn_out)
{
  __shared__ ushort sK[2][64 * 64];  // [kv][d] chunk-swizzled, double-buffered
  __shared__ ushort sV[2][64 * 64];  // [d][kv] chunk-swizzled
  __shared__ ushort sPt[8][16][72];  // per-wave [i][j], +8 pad

  const int t = threadIdx.x;
  const int lane = t & 63, w = t >> 6;  // w 0..7
  const int quad = lane >> 4, l16 = lane & 15;
  const int bh = blockIdx.y, b = bh >> 4, h = bh & 15;
  const int qbase = blockIdx.x * 128;
  const int rowK = lane >> 3;
  const int csw = ((lane & 7) ^ rowK) * 8;
  const int swz = l16 & 7;

  // Q fragments (B-operand): n=l16 -> i (wave's 16 rows), k=quad*8+j -> d
  bf16x8 qf[2];
#pragma unroll
  for (int c = 0; c < 2; ++c)
    qf[c] = *(const bf16x8*)&qk[
        ((size_t)(b * NS + qbase + w * 16 + l16)) * 2048 +
        h * 64 + c * 32 + quad * 8];

  bf16x8 ones;
  { union { bf16x8 v; ushort s[8]; } ou;
#pragma unroll
    for (int i = 0; i < 8; ++i) ou.s[i] = 0x3F80;
    ones = ou.v; }

  // kb-invariant pattern masks: masked <=> (i-j) % 32 == 0.
  // i = qbase + w*16 + l16; j = kvbase + mt*16 + quad*4 + ri.
  // qbase%128==0, kvbase%64==0 drop mod 32; w*16 does NOT -> keep (w&1)*16.
  unsigned amask[4][2];
#pragma unroll
  for (int mt = 0; mt < 4; ++mt)
#pragma unroll
    for (int hf = 0; hf < 2; ++hf) {
      int r0 = hf * 2, r1 = hf * 2 + 1;
      int base = (w & 1) * 16 + l16 - mt * 16 - quad * 4;
      unsigned m = 0xFFFFFFFFu;
      if (((base - r0) & 31) == 0) m &= 0xFFFF0000u;
      if (((base - r1) & 31) == 0) m &= 0x0000FFFFu;
      amask[mt][hf] = m;
    }

  const int ib64 = (qbase + w * 16) >> 6;  // wave-uniform boundary kv-tile

  f32x4 oacc[4];
#pragma unroll
  for (int dt = 0; dt < 4; ++dt) oacc[dt] = (f32x4){0.f, 0.f, 0.f, 0.f};
  f32x4 lsum = (f32x4){0.f, 0.f, 0.f, 0.f};

  stage_kv(qk, vt, sK[0], sV[0], b, h, 0, w, rowK, csw);

  for (int kb = 0; kb < NS / 64; ++kb) {
    const int cur = kb & 1;
    const int kvbase = kb * 64;
    __syncthreads();  // buf[cur] staged; prefetch below overlaps compute
    if (kb < NS / 64 - 1)
      stage_kv(qk, vt, sK[cur ^ 1], sV[cur ^ 1], b, h, kvbase + 64, w, rowK, csw);

    const ushort* K = sK[cur];
    const ushort* V = sV[cur];

    // S^T = K Q^T : lane holds j = mt*16 + quad*4 + ri, i = l16
    f32x4 st[4];
#pragma unroll
    for (int mt = 0; mt < 4; ++mt) st[mt] = (f32x4){0.f, 0.f, 0.f, 0.f};
#pragma unroll
    for (int mt = 0; mt < 4; ++mt)
#pragma unroll
      for (int c = 0; c < 2; ++c) {
        bf16x8 kf = *(const bf16x8*)&K[(mt * 16 + l16) * 64 +
                                       (((c * 4 + quad) ^ swz) * 8)];
        st[mt] = __builtin_amdgcn_mfma_f32_16x16x32_bf16(
            kf, qf[c], st[mt], 0, 0, 0);
      }

    // exp2 + mask + pack pairs -> sPt (C-layout -> A-layout transform)
    if (kb < ib64) {  // fully past diagonal: pattern mask
#pragma unroll
      for (int mt = 0; mt < 4; ++mt) {
        unsigned lo = pack_bf16(EXP2F(st[mt][0]), EXP2F(st[mt][1])) &
                      amask[mt][0];
        unsigned hi = pack_bf16(EXP2F(st[mt][2]), EXP2F(st[mt][3])) &
                      amask[mt][1];
        *(uint2*)&sPt[w][l16][mt * 16 + quad * 4] = make_uint2(lo, hi);
      }
    } else if (kb > ib64) {  // above diagonal: no mask
#pragma unroll
      for (int mt = 0; mt < 4; ++mt) {
        unsigned lo = pack_bf16(EXP2F(st[mt][0]), EXP2F(st[mt][1]));
        unsigned hi = pack_bf16(EXP2F(st[mt][2]), EXP2F(st[mt][3]));
        *(uint2*)&sPt[w][l16][mt * 16 + quad * 4] = make_uint2(lo, hi);
      }
    } else {  // boundary tile: full per-element test
      int irow = qbase + w * 16 + l16;
#pragma unroll
      for (int mt = 0; mt < 4; ++mt) {
        float p[4];
#pragma unroll
        for (int ri = 0; ri < 4; ++ri) {
          int j = kvbase + mt * 16 + quad * 4 + ri;
          p[ri] = EXP2F(st[mt][ri]);
          unsigned du = (unsigned)(irow - j);
          if ((du & 0x8000001Fu) == 0u) p[ri] = 0.f;
        }
        unsigned lo = pack_bf16(p[0], p[1]);
        unsigned hi = pack_bf16(p[2], p[3]);
        *(uint2*)&sPt[w][l16][mt * 16 + quad * 4] = make_uint2(lo, hi);
      }
    }

    // O += P V ; l += P * ones (P read back in A-operand layout, wave-local)
#pragma unroll
    for (int c2 = 0; c2 < 2; ++c2) {
      bf16x8 pf = *(const bf16x8*)&sPt[w][l16][c2 * 32 + quad * 8];
      lsum = __builtin_amdgcn_mfma_f32_16x16x32_bf16(pf, ones, lsum, 0, 0, 0);
#pragma unroll
      for (int dt = 0; dt < 4; ++dt) {
        bf16x8 vf = *(const bf16x8*)&V[(dt * 16 + l16) * 64 +
                                       (((c2 * 4 + quad) ^ swz) * 8)];
        oacc[dt] = __builtin_amdgcn_mfma_f32_16x16x32_bf16(
            pf, vf, oacc[dt], 0, 0, 0);
      }
    }
  }

  // epilogue: O / l   (lane holds i = quad*4 + ri, d = dt*16 + l16)
#pragma unroll
  for (int ri = 0; ri < 4; ++ri) {
    float inv = __builtin_amdgcn_rcpf(lsum[ri]);
    int ig = qbase + w * 16 + quad * 4 + ri;
#pragma unroll
    for (int dt = 0; dt < 4; ++dt)
      attn_out[(size_t)(b * NS + ig) * 1024 + h * 64 + dt * 16 + l16] =
          f32_to_bf16(oacc[dt][ri] * inv);
  }
}

// ---------------------------------------------------------------------------
extern "C" void kernel_launch(void* const* d_in, const int* in_sizes, int n_in,
                              void* d_out, int out_size, void* d_ws, size_t ws_size,
                              hipStream_t stream) {
  const float* x    = (const float*)d_in[0];  // [2,2048,1024] fp32
  const float* Wqkv = (const float*)d_in[1];  // [1024,3072]
  const float* Wout = (const float*)d_in[2];  // [1024,1024]
  const float* bout = (const float*)d_in[3];  // [1024]
  float* out = (float*)d_out;                 // [2,2048,1024] fp32

  ushort* qk    = (ushort*)d_ws;                 // 4096*2048 = 16 MiB
  ushort* vt    = qk + (size_t)4096 * 2048;      // 1024*4096 = 8 MiB
  ushort* xb    = vt + (size_t)1024 * 4096;      // 8 MiB (reused as attnb)
  ushort* wqkvT = xb + (size_t)4096 * 1024;      // 3072*1024 = 6 MiB
  ushort* woutT = wqkvT + (size_t)3072 * 1024;   // 1024*1024 = 2 MiB
  ushort* attnb = xb;

  // prep: x->bf16 + W_qkv^T (Q cols pre-scaled) + W_out^T
  prep<<<6144, 256, 0, stream>>>(x, Wqkv, Wout, xb, wqkvT, woutT);
  // qk (512 TM=128 blocks) + V^T (512 TM=64 blocks), one launch, 4 blocks/CU
  gemm_qkvt<<<1024, 256, 0, stream>>>(xb, wqkvT, qk, vt);
  // attention (512 threads: 8 waves x 16 q-rows)
  attn_kernel<<<dim3(NS / 128, 32), 512, 0, stream>>>(qk, vt, attnb);
  // out = attnb @ WoutT^T + b_out (fp32), 64x128 tiles, XCD-swizzled
  gemm_out<<<512, 256, 0, stream>>>(attnb, woutT, bout, out);
}